// Round 6
// baseline (2323.916 us; speedup 1.0000x reference)
//
#include <hip/hip_runtime.h>
#include <hip/hip_fp16.h>

#define N_NODES 500000
#define N_EDGES 1000000
#define N_GRAPHS 20000

typedef _Float16 f16x8 __attribute__((ext_vector_type(8)));
typedef float f32x4 __attribute__((ext_vector_type(4)));

__global__ __launch_bounds__(256) void fill_u32(unsigned* p, unsigned v, int n) {
  int i = blockIdx.x * 256 + threadIdx.x;
  if (i < n) p[i] = v;
}

__global__ __launch_bounds__(256) void hist_dst(const int* __restrict__ dst, int* cnt, int e) {
  int i = blockIdx.x * 256 + threadIdx.x;
  if (i < e) atomicAdd(&cnt[dst[i]], 1);
}

// zero npad u32 words per row at [r*stride + off .. +npad)
__global__ __launch_bounds__(256) void pad_zero_u32(unsigned* p, int stride, int off, int npad, int rows) {
  int i = blockIdx.x * 256 + threadIdx.x;
  if (i >= rows * npad) return;
  int r = i / npad, j = i - r * npad;
  p[(size_t)r * stride + off + j] = 0u;
}

// ---- 2-level exclusive scan over deg[N] (1024 elems/block) ----
__global__ __launch_bounds__(256) void scanA(const int* __restrict__ deg, int* __restrict__ loc,
                                             int* __restrict__ partials, int n) {
  __shared__ int ts[256];
  int b = blockIdx.x, t = threadIdx.x;
  int base = b * 1024 + t * 4;
  int v[4], s = 0;
#pragma unroll
  for (int j = 0; j < 4; ++j) {
    v[j] = (base + j < n) ? deg[base + j] : 0;
    s += v[j];
  }
  ts[t] = s;
  __syncthreads();
  for (int off = 1; off < 256; off <<= 1) {
    int x = (t >= off) ? ts[t - off] : 0;
    __syncthreads();
    ts[t] += x;
    __syncthreads();
  }
  if (t == 255) partials[b] = ts[255];
  int run = ts[t] - s;  // exclusive
#pragma unroll
  for (int j = 0; j < 4; ++j) {
    if (base + j < n) loc[base + j] = run;
    run += v[j];
  }
}

__global__ __launch_bounds__(512) void scanB(int* partials, int nb) {
  __shared__ int s[512];
  int t = threadIdx.x;
  s[t] = (t < nb) ? partials[t] : 0;
  __syncthreads();
  if (t == 0) {
    int run = 0;
    for (int i = 0; i < nb; ++i) { int v = s[i]; s[i] = run; run += v; }
  }
  __syncthreads();
  if (t < nb) partials[t] = s[t];
}

__global__ __launch_bounds__(256) void scanC(int* __restrict__ rowptr, const int* __restrict__ partials,
                                             int* __restrict__ cur, int n, int e) {
  int i = blockIdx.x * 256 + threadIdx.x;
  if (i < n) {
    int v = rowptr[i] + partials[i >> 10];
    rowptr[i] = v;
    cur[i] = v;
  }
  if (i == 0) rowptr[n] = e;
}

__global__ __launch_bounds__(256) void dinv_k(const int* __restrict__ rowptr, float* dinv, int n) {
  int i = blockIdx.x * 256 + threadIdx.x;
  if (i < n) dinv[i] = rsqrtf(1.0f + (float)(rowptr[i + 1] - rowptr[i]));
}

__global__ __launch_bounds__(256) void bucket(const int* __restrict__ src, const int* __restrict__ dst,
                                              int* __restrict__ cur, int* __restrict__ ssrc, int e) {
  int i = blockIdx.x * 256 + threadIdx.x;
  if (i < e) ssrc[atomicAdd(&cur[dst[i]], 1)] = src[i];
}

// gstart[g] = first node index of graph g (batch sorted); gstart[G] = N
__global__ __launch_bounds__(256) void graph_starts(const int* __restrict__ batch,
                                                    int* __restrict__ gstart, int n) {
  int i = blockIdx.x * 256 + threadIdx.x;
  if (i < n) {
    int b = batch[i];
    int bp = (i == 0) ? -1 : batch[i - 1];
    for (int g = bp + 1; g <= b; ++g) gstart[g] = i;
  } else if (i == n) {
    int bl = batch[n - 1];
    for (int g = bl + 1; g <= N_GRAPHS; ++g) gstart[g] = n;
  }
}

// WT[c][k] = f16(W[k][c]) zero-padded to [CP][KP]; total = CP*KP
__global__ __launch_bounds__(256) void wt_conv(const float* __restrict__ W, _Float16* __restrict__ WT,
                                               int K, int Nout, int ldw, int KP, int total) {
  int i = blockIdx.x * 256 + threadIdx.x;
  if (i >= total) return;
  int c = i / KP, k = i - c * KP;
  WT[i] = (k < K && c < Nout) ? (_Float16)W[(size_t)k * ldw + c] : (_Float16)0.f;
}

// Xh[n, 0:96] = f16(x[n, 0:78]), zero pad
__global__ __launch_bounds__(256) void xconv(const float* __restrict__ x, _Float16* __restrict__ Xh) {
  unsigned idx = blockIdx.x * 256u + threadIdx.x;
  if (idx >= (unsigned)N_NODES * 48u) return;
  unsigned n = idx / 48u, c2 = idx - n * 48u;
  __half2 h = __floats2half2_rn(0.f, 0.f);
  if (c2 < 39u) {
    float2 v = *reinterpret_cast<const float2*>(x + (size_t)n * 78 + 2 * c2);
    h = __floats2half2_rn(v.x, v.y);
  }
  *reinterpret_cast<__half2*>((__half*)Xh + (size_t)n * 96 + 2 * c2) = h;
}

// Full-K-staged MFMA GEMM. in: [M, KP] f16 zero-padded. WT: [CP, KP] f16 (pre-offset
// by host for column chunk). Tile 128 rows x 80 cols, 4 waves. No in-loop barriers
// (KP<=160); KP=320 stages A in two halves.
// OUT_MODE 0: v*rs[row] -> f16 outp (stride LDO)
// OUT_MODE 1: relu(v+bo[oc]) -> f16 outp (stride LDO)
template <int KP, int OUT_MODE>
__global__ __launch_bounds__(256) void gemm_full(
    const _Float16* __restrict__ in, const _Float16* __restrict__ WT,
    void* __restrict__ outp, const float* __restrict__ rs, const float* __restrict__ bo,
    int M, int Nout, int LDO) {
  constexpr int NHALF = (KP > 160) ? 2 : 1;
  constexpr int AHALF = KP / NHALF;
  __shared__ _Float16 As[128][AHALF + 8];
  __shared__ _Float16 Bs[80][KP + 8];
  const int tid = threadIdx.x;
  const int lane = tid & 63;
  const int wid = tid >> 6;
  const int row0 = blockIdx.y * 128;
  const int col0 = blockIdx.x * 80;
  const f32x4 z4 = {0.f, 0.f, 0.f, 0.f};
  f32x4 acc[2][5];
#pragma unroll
  for (int a = 0; a < 2; ++a)
#pragma unroll
    for (int b = 0; b < 5; ++b) acc[a][b] = z4;

  // ---- stage full B once (uint4 from pre-transposed f16 weights) ----
  const _Float16* wt = WT + (size_t)col0 * KP;
  for (int i = tid; i < 10 * KP; i += 256) {
    int c = i / (KP / 8), kc = (i - c * (KP / 8)) * 8;
    *reinterpret_cast<uint4*>(&Bs[c][kc]) =
        *reinterpret_cast<const uint4*>(wt + (size_t)c * KP + kc);
  }

#pragma unroll
  for (int h = 0; h < NHALF; ++h) {
    if (h) __syncthreads();
    // ---- stage A half (full K for KP<=160) ----
    for (int i = tid; i < 16 * AHALF; i += 256) {
      int r = i / (AHALF / 8), kc = (i - r * (AHALF / 8)) * 8;
      int gr = row0 + r;
      uint4 v = {0u, 0u, 0u, 0u};
      if (gr < M)
        v = *reinterpret_cast<const uint4*>(in + (size_t)gr * KP + h * AHALF + kc);
      *reinterpret_cast<uint4*>(&As[r][kc]) = v;
    }
    __syncthreads();
    // ---- pure compute: no barriers ----
#pragma unroll
    for (int s = 0; s < AHALF / 32; ++s) {
      const int ka = s * 32 + (lane >> 4) * 8;
      const int kb = h * AHALF + ka;
      f16x8 af[2], bf[5];
#pragma unroll
      for (int rf = 0; rf < 2; ++rf)
        af[rf] = *reinterpret_cast<const f16x8*>(&As[wid * 32 + rf * 16 + (lane & 15)][ka]);
#pragma unroll
      for (int nf = 0; nf < 5; ++nf)
        bf[nf] = *reinterpret_cast<const f16x8*>(&Bs[nf * 16 + (lane & 15)][kb]);
#pragma unroll
      for (int rf = 0; rf < 2; ++rf)
#pragma unroll
        for (int nf = 0; nf < 5; ++nf)
          acc[rf][nf] = __builtin_amdgcn_mfma_f32_16x16x32_f16(af[rf], bf[nf], acc[rf][nf], 0, 0, 0);
    }
  }

  // ---- epilogue: C/D col=lane&15, row=(lane>>4)*4+reg ----
#pragma unroll
  for (int rf = 0; rf < 2; ++rf) {
#pragma unroll
    for (int j = 0; j < 4; ++j) {
      int gr = row0 + wid * 32 + rf * 16 + (lane >> 4) * 4 + j;
      if (gr >= M) continue;
      float sc = (OUT_MODE == 0) ? rs[gr] : 0.f;
#pragma unroll
      for (int nf = 0; nf < 5; ++nf) {
        int oc = col0 + nf * 16 + (lane & 15);
        if (oc >= Nout) continue;
        float v = acc[rf][nf][j];
        if (OUT_MODE == 0) {
          ((_Float16*)outp)[(size_t)gr * LDO + oc] = (_Float16)(v * sc);
        } else {
          ((_Float16*)outp)[(size_t)gr * LDO + oc] = (_Float16)fmaxf(v + bo[oc], 0.f);
        }
      }
    }
  }
}

// Per-K-step staged GEMM (kept for FC2, K=1024). TIN f16, OUT_MODE 2: v+bo -> f32.
__global__ __launch_bounds__(256) void gemm_steps(
    const _Float16* __restrict__ in, const float* __restrict__ W,
    float* __restrict__ outp, const float* __restrict__ bo,
    int M, int K, int KP, int Nout, int ldw, int LDO) {
  __shared__ _Float16 As[128][40];
  __shared__ _Float16 Bs[80][40];
  const int tid = threadIdx.x;
  const int lane = tid & 63;
  const int wid = tid >> 6;
  const int row0 = blockIdx.y * 128;
  const int col0 = blockIdx.x * 80;
  const f32x4 z4 = {0.f, 0.f, 0.f, 0.f};
  f32x4 acc[2][5];
#pragma unroll
  for (int a = 0; a < 2; ++a)
#pragma unroll
    for (int b = 0; b < 5; ++b) acc[a][b] = z4;

  const int nsteps = (K + 31) >> 5;
  for (int s = 0; s < nsteps; ++s) {
    const int k0 = s << 5;
#pragma unroll
    for (int i = 0; i < 2; ++i) {
      int id = tid + i * 256;
      int r = id >> 2, kc = (id & 3) << 3;
      int gr = row0 + r, gk = k0 + kc;
      uint4 v = {0u, 0u, 0u, 0u};
      if (gr < M && gk + 8 <= KP)
        v = *reinterpret_cast<const uint4*>(in + (size_t)gr * KP + gk);
      *reinterpret_cast<uint4*>(&As[r][kc]) = v;
    }
#pragma unroll
    for (int i = 0; i < 10; ++i) {
      int id = tid + i * 256;
      int k = id / 80, c = id - k * 80;
      float v = 0.f;
      if (k0 + k < K && col0 + c < Nout)
        v = W[(size_t)(k0 + k) * ldw + col0 + c];
      Bs[c][k] = (_Float16)v;
    }
    __syncthreads();
    f16x8 af[2], bf[5];
#pragma unroll
    for (int rf = 0; rf < 2; ++rf)
      af[rf] = *reinterpret_cast<const f16x8*>(&As[wid * 32 + rf * 16 + (lane & 15)][(lane >> 4) * 8]);
#pragma unroll
    for (int nf = 0; nf < 5; ++nf)
      bf[nf] = *reinterpret_cast<const f16x8*>(&Bs[nf * 16 + (lane & 15)][(lane >> 4) * 8]);
#pragma unroll
    for (int rf = 0; rf < 2; ++rf)
#pragma unroll
      for (int nf = 0; nf < 5; ++nf)
        acc[rf][nf] = __builtin_amdgcn_mfma_f32_16x16x32_f16(af[rf], bf[nf], acc[rf][nf], 0, 0, 0);
    __syncthreads();
  }

#pragma unroll
  for (int rf = 0; rf < 2; ++rf) {
#pragma unroll
    for (int j = 0; j < 4; ++j) {
      int gr = row0 + wid * 32 + rf * 16 + (lane >> 4) * 4 + j;
      if (gr >= M) continue;
#pragma unroll
      for (int nf = 0; nf < 5; ++nf) {
        int oc = col0 + nf * 16 + (lane & 15);
        if (oc >= Nout) continue;
        outp[(size_t)gr * LDO + oc] = acc[rf][nf][j] + bo[oc];
      }
    }
  }
}

// Fused segment-sum + transform (layers 1-2). hs stride 80 fp16.
// dsth[n, coff+c] = fp16(relu(dinv[n]*(hs[n]+Σ_seg hs[ssrc]) + b[coff+c]))
__global__ __launch_bounds__(256) void aggregate78(
    const _Float16* __restrict__ hs, const int* __restrict__ rowptr,
    const int* __restrict__ ssrc, const float* __restrict__ dinv,
    const float* __restrict__ b, _Float16* __restrict__ dsth, int ldo, int coff) {
  unsigned idx = blockIdx.x * 256u + threadIdx.x;
  if (idx >= (unsigned)N_NODES * 39u) return;
  unsigned n = idx / 39u, c = idx - n * 39u;
  const unsigned co = 2u * c;
  __half2 h0 = *reinterpret_cast<const __half2*>(hs + (size_t)n * 80 + co);
  float ax = __half2float(h0.x), ay = __half2float(h0.y);
  int s0 = rowptr[n], s1 = rowptr[n + 1];
  for (int i = s0; i < s1; ++i) {
    int s = ssrc[i];
    __half2 v = *reinterpret_cast<const __half2*>(hs + (size_t)s * 80 + co);
    ax += __half2float(v.x);
    ay += __half2float(v.y);
  }
  float di = dinv[n];
  float r0 = fmaxf(fmaf(di, ax, b[coff + co]), 0.f);
  float r1 = fmaxf(fmaf(di, ay, b[coff + co + 1]), 0.f);
  *reinterpret_cast<__half2*>(dsth + (size_t)n * ldo + coff + co) = __floats2half2_rn(r0, r1);
}

// Layer-3 pool: one wave per graph, no atomics.
template <int LAST>
__global__ __launch_bounds__(256) void pool_graph(
    const _Float16* __restrict__ hs, const int* __restrict__ rowptr,
    const int* __restrict__ ssrc, const float* __restrict__ dinv,
    const float* __restrict__ b3, const int* __restrict__ gstart,
    _Float16* __restrict__ GA, int coff) {
  const int w = threadIdx.x >> 6, lane = threadIdx.x & 63;
  const int g = blockIdx.x * 4 + w;
  if (g >= N_GRAPHS) return;
  const int n0 = gstart[g], n1 = gstart[g + 1];
  if (lane < 39) {
    const int co = 2 * lane;
    const float bx = b3[coff + co], by = b3[coff + co + 1];
    float accx = 0.f, accy = 0.f;
    for (int n = n0; n < n1; ++n) {
      __half2 h = *reinterpret_cast<const __half2*>(hs + (size_t)n * 80 + co);
      float ax = __half2float(h.x), ay = __half2float(h.y);
      int e0 = rowptr[n], e1 = rowptr[n + 1];
      for (int i = e0; i < e1; ++i) {
        int s = ssrc[i];
        __half2 v = *reinterpret_cast<const __half2*>(hs + (size_t)s * 80 + co);
        ax += __half2float(v.x);
        ay += __half2float(v.y);
      }
      float di = dinv[n];
      accx += fmaxf(fmaf(di, ax, bx), 0.f);
      accy += fmaxf(fmaf(di, ay, by), 0.f);
    }
    float gi = 1.0f / fmaxf((float)(n1 - n0), 1.0f);
    *reinterpret_cast<__half2*>(GA + (size_t)g * 320 + coff + co) =
        __floats2half2_rn(accx * gi, accy * gi);
  } else if (LAST && lane < 43) {
    *reinterpret_cast<__half2*>(GA + (size_t)g * 320 + 312 + 2 * (lane - 39)) =
        __floats2half2_rn(0.f, 0.f);
  }
}

extern "C" void kernel_launch(void* const* d_in, const int* in_sizes, int n_in,
                              void* d_out, int out_size, void* d_ws, size_t ws_size,
                              hipStream_t stream) {
  const float* x   = (const float*)d_in[0];
  const int* ei    = (const int*)d_in[1];
  const int* batch = (const int*)d_in[2];
  const float* W1 = (const float*)d_in[3];
  const float* b1 = (const float*)d_in[4];
  const float* W2 = (const float*)d_in[5];
  const float* b2 = (const float*)d_in[6];
  const float* W3 = (const float*)d_in[7];
  const float* b3 = (const float*)d_in[8];
  const float* fW1 = (const float*)d_in[9];
  const float* fb1 = (const float*)d_in[10];
  const float* fW2 = (const float*)d_in[11];
  const float* fb2 = (const float*)d_in[12];
  float* out = (float*)d_out;

  const int Nn = N_NODES, E = N_EDGES, G = N_GRAPHS;
  const int* src = ei;
  const int* dst = ei + E;

  // ---- workspace layout (~360 MB). Xh aliases AGG2h; fc1 aliases HSh. ----
  _Float16* AGG2h = (_Float16*)d_ws;                      // [N,160] L3 input
  _Float16* Xh    = AGG2h;                                // [N,96]  (dead before AGG2h written)
  _Float16* AGG1h = AGG2h + (size_t)Nn * 160;             // [N,96]  L2 input
  _Float16* HSh   = AGG1h + (size_t)Nn * 96;              // [N,80]  hs chunk
  _Float16* fc1   = HSh;                                  // [G,1024] (after last pool)
  _Float16* GA    = HSh + (size_t)Nn * 80;                // [G,320]
  _Float16* W1T   = GA + (size_t)G * 320;                 // [80][96]
  _Float16* W2T   = W1T + 80 * 96;                        // [160][96]
  _Float16* W3T   = W2T + 160 * 96;                       // [320][160]
  _Float16* fW1T  = W3T + 320 * 160;                      // [1040][320]
  float* dinv     = (float*)(fW1T + 1040 * 320);          // [N]
  int* rowptr     = (int*)(dinv + Nn);                    // [N+1]
  int* cur        = rowptr + Nn + 1;                      // [N]
  int* ssrc       = cur + Nn;                             // [E]
  int* partials   = ssrc + E;                             // [512]
  int* gstart     = partials + 512;                       // [G+1]

  dim3 blk(256);
  const int gN39 = (int)(((unsigned)Nn * 39u + 255u) / 256u);
  const dim3 nodeGrid(1, (Nn + 127) / 128);
  const int NB = (Nn + 1023) / 1024;  // 489
  const int poolGrid = (G + 3) / 4;

  // ---- CSR build (dst-sorted src list) ----
  fill_u32<<<(Nn + 255) / 256, blk, 0, stream>>>((unsigned*)cur, 0u, Nn);
  hist_dst<<<(E + 255) / 256, blk, 0, stream>>>(dst, cur, E);
  scanA<<<NB, blk, 0, stream>>>(cur, rowptr, partials, Nn);
  scanB<<<1, 512, 0, stream>>>(partials, NB);
  scanC<<<(Nn + 255) / 256, blk, 0, stream>>>(rowptr, partials, cur, Nn, E);
  dinv_k<<<(Nn + 255) / 256, blk, 0, stream>>>(rowptr, dinv, Nn);
  bucket<<<(E + 255) / 256, blk, 0, stream>>>(src, dst, cur, ssrc, E);
  graph_starts<<<(Nn + 256) / 256, blk, 0, stream>>>(batch, gstart, Nn);

  // ---- fp16 transposed weights ----
  wt_conv<<<(80 * 96 + 255) / 256, blk, 0, stream>>>(W1, W1T, 78, 78, 78, 96, 80 * 96);
  wt_conv<<<(160 * 96 + 255) / 256, blk, 0, stream>>>(W2, W2T, 78, 156, 156, 96, 160 * 96);
  wt_conv<<<(320 * 160 + 255) / 256, blk, 0, stream>>>(W3, W3T, 156, 312, 312, 160, 320 * 160);
  wt_conv<<<(1040 * 320 + 255) / 256, blk, 0, stream>>>(fW1, fW1T, 312, 1024, 1024, 320, 1040 * 320);

  // ---- x -> f16 [N,96]; AGG1h pad cols ----
  xconv<<<(int)(((unsigned)Nn * 48u + 255u) / 256u), blk, 0, stream>>>(x, Xh);
  pad_zero_u32<<<((Nn * 9) + 255) / 256, blk, 0, stream>>>((unsigned*)AGG1h, 48, 39, 9, Nn);

  // ---- layer 1 ----
  gemm_full<96, 0><<<nodeGrid, blk, 0, stream>>>(Xh, W1T, HSh, dinv, nullptr, Nn, 78, 80);
  // Xh dead now; safe to touch AGG2h pad cols (156..159)
  pad_zero_u32<<<((Nn * 2) + 255) / 256, blk, 0, stream>>>((unsigned*)AGG2h, 80, 78, 2, Nn);
  aggregate78<<<gN39, blk, 0, stream>>>(HSh, rowptr, ssrc, dinv, b1, AGG1h, 96, 0);

  // ---- layer 2 (2 chunks of 78) ----
  for (int c = 0; c < 2; ++c) {
    gemm_full<96, 0><<<nodeGrid, blk, 0, stream>>>(
        AGG1h, W2T + (size_t)(78 * c) * 96, HSh, dinv, nullptr, Nn, 78, 80);
    aggregate78<<<gN39, blk, 0, stream>>>(HSh, rowptr, ssrc, dinv, b2, AGG2h, 160, 78 * c);
  }

  // ---- layer 3 (4 chunks of 78) + per-graph register pool ----
  for (int c = 0; c < 4; ++c) {
    gemm_full<160, 0><<<nodeGrid, blk, 0, stream>>>(
        AGG2h, W3T + (size_t)(78 * c) * 160, HSh, dinv, nullptr, Nn, 78, 80);
    if (c == 3)
      pool_graph<1><<<poolGrid, blk, 0, stream>>>(HSh, rowptr, ssrc, dinv, b3, gstart, GA, 78 * c);
    else
      pool_graph<0><<<poolGrid, blk, 0, stream>>>(HSh, rowptr, ssrc, dinv, b3, gstart, GA, 78 * c);
  }

  // ---- FC1: relu(GA @ fW1 + fb1) -> fc1 f16 (overlays HSh) ----
  {
    dim3 g(1024 / 80 + 1, (G + 127) / 128);  // 13 x 157
    gemm_full<320, 1><<<g, blk, 0, stream>>>(GA, fW1T, fc1, nullptr, fb1, G, 1024, 1024);
  }
  // ---- FC2: out = fc1 @ fW2 + fb2 ----
  {
    dim3 g((128 + 79) / 80, (G + 127) / 128);  // 2 x 157
    gemm_steps<<<g, blk, 0, stream>>>(fc1, fW2, out, fb2, G, 1024, 1024, 128, 128, 128);
  }
}

// Round 7
// 1980.107 us; speedup vs baseline: 1.1736x; 1.1736x over previous
//
#include <hip/hip_runtime.h>
#include <hip/hip_fp16.h>

#define N_NODES 500000
#define N_EDGES 1000000
#define N_GRAPHS 20000

typedef _Float16 f16x8 __attribute__((ext_vector_type(8)));
typedef float f32x4 __attribute__((ext_vector_type(4)));

__global__ __launch_bounds__(256) void fill_u32(unsigned* p, unsigned v, int n) {
  int i = blockIdx.x * 256 + threadIdx.x;
  if (i < n) p[i] = v;
}

__global__ __launch_bounds__(256) void hist_dst(const int* __restrict__ dst, int* cnt, int e) {
  int i = blockIdx.x * 256 + threadIdx.x;
  if (i < e) atomicAdd(&cnt[dst[i]], 1);
}

// zero npad u32 words per row at [r*stride + off .. +npad)
__global__ __launch_bounds__(256) void pad_zero_u32(unsigned* p, int stride, int off, int npad, int rows) {
  int i = blockIdx.x * 256 + threadIdx.x;
  if (i >= rows * npad) return;
  int r = i / npad, j = i - r * npad;
  p[(size_t)r * stride + off + j] = 0u;
}

// ---- 2-level exclusive scan over deg[N] (1024 elems/block) ----
__global__ __launch_bounds__(256) void scanA(const int* __restrict__ deg, int* __restrict__ loc,
                                             int* __restrict__ partials, int n) {
  __shared__ int ts[256];
  int b = blockIdx.x, t = threadIdx.x;
  int base = b * 1024 + t * 4;
  int v[4], s = 0;
#pragma unroll
  for (int j = 0; j < 4; ++j) {
    v[j] = (base + j < n) ? deg[base + j] : 0;
    s += v[j];
  }
  ts[t] = s;
  __syncthreads();
  for (int off = 1; off < 256; off <<= 1) {
    int x = (t >= off) ? ts[t - off] : 0;
    __syncthreads();
    ts[t] += x;
    __syncthreads();
  }
  if (t == 255) partials[b] = ts[255];
  int run = ts[t] - s;  // exclusive
#pragma unroll
  for (int j = 0; j < 4; ++j) {
    if (base + j < n) loc[base + j] = run;
    run += v[j];
  }
}

__global__ __launch_bounds__(512) void scanB(int* partials, int nb) {
  __shared__ int s[512];
  int t = threadIdx.x;
  s[t] = (t < nb) ? partials[t] : 0;
  __syncthreads();
  if (t == 0) {
    int run = 0;
    for (int i = 0; i < nb; ++i) { int v = s[i]; s[i] = run; run += v; }
  }
  __syncthreads();
  if (t < nb) partials[t] = s[t];
}

__global__ __launch_bounds__(256) void scanC(int* __restrict__ rowptr, const int* __restrict__ partials,
                                             int* __restrict__ cur, int n, int e) {
  int i = blockIdx.x * 256 + threadIdx.x;
  if (i < n) {
    int v = rowptr[i] + partials[i >> 10];
    rowptr[i] = v;
    cur[i] = v;
  }
  if (i == 0) rowptr[n] = e;
}

__global__ __launch_bounds__(256) void dinv_k(const int* __restrict__ rowptr, float* dinv, int n) {
  int i = blockIdx.x * 256 + threadIdx.x;
  if (i < n) dinv[i] = rsqrtf(1.0f + (float)(rowptr[i + 1] - rowptr[i]));
}

__global__ __launch_bounds__(256) void bucket(const int* __restrict__ src, const int* __restrict__ dst,
                                              int* __restrict__ cur, int* __restrict__ ssrc, int e) {
  int i = blockIdx.x * 256 + threadIdx.x;
  if (i < e) ssrc[atomicAdd(&cur[dst[i]], 1)] = src[i];
}

// gstart[g] = first node index of graph g (batch sorted); gstart[G] = N
__global__ __launch_bounds__(256) void graph_starts(const int* __restrict__ batch,
                                                    int* __restrict__ gstart, int n) {
  int i = blockIdx.x * 256 + threadIdx.x;
  if (i < n) {
    int b = batch[i];
    int bp = (i == 0) ? -1 : batch[i - 1];
    for (int g = bp + 1; g <= b; ++g) gstart[g] = i;
  } else if (i == n) {
    int bl = batch[n - 1];
    for (int g = bl + 1; g <= N_GRAPHS; ++g) gstart[g] = n;
  }
}

// WT[c][k] = f16(W[k][c]) zero-padded to [CP][KP]; total = CP*KP
__global__ __launch_bounds__(256) void wt_conv(const float* __restrict__ W, _Float16* __restrict__ WT,
                                               int K, int Nout, int ldw, int KP, int total) {
  int i = blockIdx.x * 256 + threadIdx.x;
  if (i >= total) return;
  int c = i / KP, k = i - c * KP;
  WT[i] = (k < K && c < Nout) ? (_Float16)W[(size_t)k * ldw + c] : (_Float16)0.f;
}

// Xh[n, 0:96] = f16(x[n, 0:78]), zero pad
__global__ __launch_bounds__(256) void xconv(const float* __restrict__ x, _Float16* __restrict__ Xh) {
  unsigned idx = blockIdx.x * 256u + threadIdx.x;
  if (idx >= (unsigned)N_NODES * 48u) return;
  unsigned n = idx / 48u, c2 = idx - n * 48u;
  __half2 h = __floats2half2_rn(0.f, 0.f);
  if (c2 < 39u) {
    float2 v = *reinterpret_cast<const float2*>(x + (size_t)n * 78 + 2 * c2);
    h = __floats2half2_rn(v.x, v.y);
  }
  *reinterpret_cast<__half2*>((__half*)Xh + (size_t)n * 96 + 2 * c2) = h;
}

// MFMA GEMM, uniform K-step of 96. in: [M, KP] f16 zero-padded. WT: [*, KP] f16
// pre-transposed, rows = output cols (zero-padded rows). Tile 128x80, 4 waves,
// LDS 43 KB -> 3 blocks/CU. KP must be a multiple of 96.
// OUT_MODE 0: v*rs[row] -> f16 outp ; 1: relu(v+bo) -> f16 ; 2: v+bo -> f32
template <int KP, int OUT_MODE>
__global__ __launch_bounds__(256) void gemm_full(
    const _Float16* __restrict__ in, const _Float16* __restrict__ WT,
    void* __restrict__ outp, const float* __restrict__ rs, const float* __restrict__ bo,
    int M, int Nout, int LDO) {
  constexpr int NSTEP = KP / 96;
  __shared__ _Float16 As[128][104];
  __shared__ _Float16 Bs[80][104];
  const int tid = threadIdx.x;
  const int lane = tid & 63;
  const int wid = tid >> 6;
  const int row0 = blockIdx.y * 128;
  const int col0 = blockIdx.x * 80;
  const _Float16* wt = WT + (size_t)col0 * KP;
  const f32x4 z4 = {0.f, 0.f, 0.f, 0.f};
  f32x4 acc[2][5];
#pragma unroll
  for (int a = 0; a < 2; ++a)
#pragma unroll
    for (int b = 0; b < 5; ++b) acc[a][b] = z4;

  for (int t = 0; t < NSTEP; ++t) {
    if (t) __syncthreads();
    // ---- stage A: 128 rows x 96 k = 1536 uint4 ----
#pragma unroll
    for (int i = 0; i < 6; ++i) {
      int id = tid + i * 256;
      int r = id / 12, kc = (id - r * 12) * 8;
      int gr = row0 + r;
      uint4 v = {0u, 0u, 0u, 0u};
      if (gr < M)
        v = *reinterpret_cast<const uint4*>(in + (size_t)gr * KP + t * 96 + kc);
      *reinterpret_cast<uint4*>(&As[r][kc]) = v;
    }
    // ---- stage B: 80 cols x 96 k = 960 uint4 ----
#pragma unroll
    for (int i = 0; i < 4; ++i) {
      int id = tid + i * 256;
      if (id < 960) {
        int cc = id / 12, kc = (id - cc * 12) * 8;
        *reinterpret_cast<uint4*>(&Bs[cc][kc]) =
            *reinterpret_cast<const uint4*>(wt + (size_t)cc * KP + t * 96 + kc);
      }
    }
    __syncthreads();
#pragma unroll
    for (int s = 0; s < 3; ++s) {
      const int ka = s * 32 + (lane >> 4) * 8;
      f16x8 af[2], bf[5];
#pragma unroll
      for (int rf = 0; rf < 2; ++rf)
        af[rf] = *reinterpret_cast<const f16x8*>(&As[wid * 32 + rf * 16 + (lane & 15)][ka]);
#pragma unroll
      for (int nf = 0; nf < 5; ++nf)
        bf[nf] = *reinterpret_cast<const f16x8*>(&Bs[nf * 16 + (lane & 15)][ka]);
#pragma unroll
      for (int rf = 0; rf < 2; ++rf)
#pragma unroll
        for (int nf = 0; nf < 5; ++nf)
          acc[rf][nf] = __builtin_amdgcn_mfma_f32_16x16x32_f16(af[rf], bf[nf], acc[rf][nf], 0, 0, 0);
    }
  }

  // ---- epilogue: C/D col=lane&15, row=(lane>>4)*4+reg ----
#pragma unroll
  for (int rf = 0; rf < 2; ++rf) {
#pragma unroll
    for (int j = 0; j < 4; ++j) {
      int gr = row0 + wid * 32 + rf * 16 + (lane >> 4) * 4 + j;
      if (gr >= M) continue;
      float sc = (OUT_MODE == 0) ? rs[gr] : 0.f;
#pragma unroll
      for (int nf = 0; nf < 5; ++nf) {
        int oc = col0 + nf * 16 + (lane & 15);
        if (oc >= Nout) continue;
        float v = acc[rf][nf][j];
        if (OUT_MODE == 0) {
          ((_Float16*)outp)[(size_t)gr * LDO + oc] = (_Float16)(v * sc);
        } else if (OUT_MODE == 1) {
          ((_Float16*)outp)[(size_t)gr * LDO + oc] = (_Float16)fmaxf(v + bo[oc], 0.f);
        } else {
          ((float*)outp)[(size_t)gr * LDO + oc] = v + bo[oc];
        }
      }
    }
  }
}

// Fused segment-sum + transform. hs stride 80 fp16; 2-way edge unroll.
// dsth[n, wcoff+c] = fp16(relu(dinv[n]*(hs[n]+Σ_seg hs[ssrc]) + b[boff+c]))
__global__ __launch_bounds__(256) void aggregate78(
    const _Float16* __restrict__ hs, const int* __restrict__ rowptr,
    const int* __restrict__ ssrc, const float* __restrict__ dinv,
    const float* __restrict__ b, _Float16* __restrict__ dsth,
    int ldo, int boff, int wcoff) {
  unsigned idx = blockIdx.x * 256u + threadIdx.x;
  if (idx >= (unsigned)N_NODES * 39u) return;
  unsigned n = idx / 39u, c = idx - n * 39u;
  const unsigned co = 2u * c;
  const __half* hrow = (const __half*)hs + co;
  __half2 h0 = *reinterpret_cast<const __half2*>(hrow + (size_t)n * 80);
  float ax = __half2float(h0.x), ay = __half2float(h0.y);
  float bx = 0.f, by = 0.f;
  int i = rowptr[n], s1 = rowptr[n + 1];
  for (; i + 2 <= s1; i += 2) {
    int sa = ssrc[i], sb = ssrc[i + 1];
    __half2 va = *reinterpret_cast<const __half2*>(hrow + (size_t)sa * 80);
    __half2 vb = *reinterpret_cast<const __half2*>(hrow + (size_t)sb * 80);
    ax += __half2float(va.x); ay += __half2float(va.y);
    bx += __half2float(vb.x); by += __half2float(vb.y);
  }
  if (i < s1) {
    int sa = ssrc[i];
    __half2 va = *reinterpret_cast<const __half2*>(hrow + (size_t)sa * 80);
    ax += __half2float(va.x); ay += __half2float(va.y);
  }
  ax += bx; ay += by;
  float di = dinv[n];
  float r0 = fmaxf(fmaf(di, ax, b[boff + co]), 0.f);
  float r1 = fmaxf(fmaf(di, ay, b[boff + co + 1]), 0.f);
  *reinterpret_cast<__half2*>(dsth + (size_t)n * ldo + wcoff + co) = __floats2half2_rn(r0, r1);
}

// Mean-pool over contiguous node range: GA[g, coff+c] = (1/cnt) Σ_n TR[n, c]
__global__ __launch_bounds__(256) void pool_seq(
    const _Float16* __restrict__ TR, const int* __restrict__ gstart,
    _Float16* __restrict__ GA, int coff) {
  unsigned idx = blockIdx.x * 256u + threadIdx.x;
  if (idx >= (unsigned)N_GRAPHS * 39u) return;
  unsigned g = idx / 39u, p = idx - g * 39u;
  int n0 = gstart[g], n1 = gstart[g + 1];
  const __half* base = (const __half*)TR + 2 * p;
  float ax = 0.f, ay = 0.f, bx = 0.f, by = 0.f;
  int n = n0;
  for (; n + 2 <= n1; n += 2) {
    __half2 va = *reinterpret_cast<const __half2*>(base + (size_t)n * 80);
    __half2 vb = *reinterpret_cast<const __half2*>(base + (size_t)(n + 1) * 80);
    ax += __half2float(va.x); ay += __half2float(va.y);
    bx += __half2float(vb.x); by += __half2float(vb.y);
  }
  if (n < n1) {
    __half2 va = *reinterpret_cast<const __half2*>(base + (size_t)n * 80);
    ax += __half2float(va.x); ay += __half2float(va.y);
  }
  float gi = 1.0f / fmaxf((float)(n1 - n0), 1.0f);
  *reinterpret_cast<__half2*>(GA + (size_t)g * 384 + coff + 2 * p) =
      __floats2half2_rn((ax + bx) * gi, (ay + by) * gi);
}

extern "C" void kernel_launch(void* const* d_in, const int* in_sizes, int n_in,
                              void* d_out, int out_size, void* d_ws, size_t ws_size,
                              hipStream_t stream) {
  const float* x   = (const float*)d_in[0];
  const int* ei    = (const int*)d_in[1];
  const int* batch = (const int*)d_in[2];
  const float* W1 = (const float*)d_in[3];
  const float* b1 = (const float*)d_in[4];
  const float* W2 = (const float*)d_in[5];
  const float* b2 = (const float*)d_in[6];
  const float* W3 = (const float*)d_in[7];
  const float* b3 = (const float*)d_in[8];
  const float* fW1 = (const float*)d_in[9];
  const float* fb1 = (const float*)d_in[10];
  const float* fW2 = (const float*)d_in[11];
  const float* fb2 = (const float*)d_in[12];
  float* out = (float*)d_out;

  const int Nn = N_NODES, E = N_EDGES, G = N_GRAPHS;
  const int* src = ei;
  const int* dst = ei + E;

  // ---- workspace layout (~395 MB) ----
  _Float16* AGG2h = (_Float16*)d_ws;                      // [N,192] L3 input
  _Float16* Xh    = AGG2h;                                // [N,96]  (dead after L1 gemm)
  _Float16* AGG1h = AGG2h + (size_t)Nn * 192;             // [N,96]  L2 input
  _Float16* TR    = AGG1h;                                // [N,80]  (after L2 gemms done)
  _Float16* HSh   = AGG1h + (size_t)Nn * 96;              // [N,80]  hs chunk
  _Float16* fc1   = HSh;                                  // [G,1056] (after last L3 agg)
  _Float16* GA    = HSh + (size_t)Nn * 80;                // [G,384]
  _Float16* W1T   = GA + (size_t)G * 384;                 // [80][96]
  _Float16* W2T   = W1T + 80 * 96;                        // [160][96]
  _Float16* W3T   = W2T + 160 * 96;                       // [320][192]
  _Float16* fW1T  = W3T + 320 * 192;                      // [1040][384]
  _Float16* fW2T  = fW1T + 1040 * 384;                    // [160][1056]
  float* dinv     = (float*)(fW2T + 160 * 1056);          // [N]
  int* rowptr     = (int*)(dinv + Nn);                    // [N+1]
  int* cur        = rowptr + Nn + 1;                      // [N]
  int* ssrc       = cur + Nn;                             // [E]
  int* partials   = ssrc + E;                             // [512]
  int* gstart     = partials + 512;                       // [G+1]

  dim3 blk(256);
  const int gN39 = (int)(((unsigned)Nn * 39u + 255u) / 256u);
  const int gG39 = (int)(((unsigned)G * 39u + 255u) / 256u);
  const dim3 nodeGrid(1, (Nn + 127) / 128);
  const int NB = (Nn + 1023) / 1024;  // 489

  // ---- CSR build (dst-sorted src list) ----
  fill_u32<<<(Nn + 255) / 256, blk, 0, stream>>>((unsigned*)cur, 0u, Nn);
  hist_dst<<<(E + 255) / 256, blk, 0, stream>>>(dst, cur, E);
  scanA<<<NB, blk, 0, stream>>>(cur, rowptr, partials, Nn);
  scanB<<<1, 512, 0, stream>>>(partials, NB);
  scanC<<<(Nn + 255) / 256, blk, 0, stream>>>(rowptr, partials, cur, Nn, E);
  dinv_k<<<(Nn + 255) / 256, blk, 0, stream>>>(rowptr, dinv, Nn);
  bucket<<<(E + 255) / 256, blk, 0, stream>>>(src, dst, cur, ssrc, E);
  graph_starts<<<(Nn + 256) / 256, blk, 0, stream>>>(batch, gstart, Nn);

  // ---- fp16 transposed weights ----
  wt_conv<<<(80 * 96 + 255) / 256, blk, 0, stream>>>(W1, W1T, 78, 78, 78, 96, 80 * 96);
  wt_conv<<<(160 * 96 + 255) / 256, blk, 0, stream>>>(W2, W2T, 78, 156, 156, 96, 160 * 96);
  wt_conv<<<(320 * 192 + 255) / 256, blk, 0, stream>>>(W3, W3T, 156, 312, 312, 192, 320 * 192);
  wt_conv<<<(1040 * 384 + 255) / 256, blk, 0, stream>>>(fW1, fW1T, 312, 1024, 1024, 384, 1040 * 384);
  wt_conv<<<(160 * 1056 + 255) / 256, blk, 0, stream>>>(fW2, fW2T, 1024, 128, 128, 1056, 160 * 1056);

  // ---- x -> f16 [N,96]; AGG1h pad cols (78..95) ----
  xconv<<<(int)(((unsigned)Nn * 48u + 255u) / 256u), blk, 0, stream>>>(x, Xh);
  pad_zero_u32<<<((Nn * 9) + 255) / 256, blk, 0, stream>>>((unsigned*)AGG1h, 48, 39, 9, Nn);

  // ---- layer 1 ----
  gemm_full<96, 0><<<nodeGrid, blk, 0, stream>>>(Xh, W1T, HSh, dinv, nullptr, Nn, 78, 80);
  // Xh dead: zero AGG2h pad cols (156..191)
  pad_zero_u32<<<((Nn * 18) + 255) / 256, blk, 0, stream>>>((unsigned*)AGG2h, 96, 78, 18, Nn);
  aggregate78<<<gN39, blk, 0, stream>>>(HSh, rowptr, ssrc, dinv, b1, AGG1h, 96, 0, 0);

  // ---- layer 2 (2 chunks of 78) ----
  for (int c = 0; c < 2; ++c) {
    gemm_full<96, 0><<<nodeGrid, blk, 0, stream>>>(
        AGG1h, W2T + (size_t)(78 * c) * 96, HSh, dinv, nullptr, Nn, 78, 80);
    aggregate78<<<gN39, blk, 0, stream>>>(HSh, rowptr, ssrc, dinv, b2, AGG2h, 192, 78 * c, 78 * c);
  }

  // ---- GA pad cols (312..383) ----
  pad_zero_u32<<<((G * 36) + 255) / 256, blk, 0, stream>>>((unsigned*)GA, 192, 156, 36, G);

  // ---- layer 3 (4 chunks of 78): gemm -> relu-transform (TR) -> seq pool ----
  for (int c = 0; c < 4; ++c) {
    gemm_full<192, 0><<<nodeGrid, blk, 0, stream>>>(
        AGG2h, W3T + (size_t)(78 * c) * 192, HSh, dinv, nullptr, Nn, 78, 80);
    aggregate78<<<gN39, blk, 0, stream>>>(HSh, rowptr, ssrc, dinv, b3, TR, 80, 78 * c, 0);
    pool_seq<<<gG39, blk, 0, stream>>>(TR, gstart, GA, 78 * c);
  }

  // ---- fc1 pad cols (1024..1055); HSh dead after last aggregate ----
  pad_zero_u32<<<((G * 16) + 255) / 256, blk, 0, stream>>>((unsigned*)fc1, 528, 512, 16, G);

  // ---- FC1: relu(GA @ fW1 + fb1) -> fc1 f16 ----
  {
    dim3 g((1024 + 79) / 80, (G + 127) / 128);  // 13 x 157
    gemm_full<384, 1><<<g, blk, 0, stream>>>(GA, fW1T, fc1, nullptr, fb1, G, 1024, 1056);
  }
  // ---- FC2: out = fc1 @ fW2 + fb2 (f32) ----
  {
    dim3 g((128 + 79) / 80, (G + 127) / 128);  // 2 x 157
    gemm_full<1056, 2><<<g, blk, 0, stream>>>(fc1, fW2T, out, nullptr, fb2, G, 128, 128);
  }
}

// Round 8
// 1670.347 us; speedup vs baseline: 1.3913x; 1.1854x over previous
//
#include <hip/hip_runtime.h>
#include <hip/hip_fp16.h>

#define N_NODES 500000
#define N_EDGES 1000000
#define N_GRAPHS 20000

typedef _Float16 f16x8 __attribute__((ext_vector_type(8)));
typedef float f32x4 __attribute__((ext_vector_type(4)));

__global__ __launch_bounds__(256) void fill_u32(unsigned* p, unsigned v, int n) {
  int i = blockIdx.x * 256 + threadIdx.x;
  if (i < n) p[i] = v;
}

__global__ __launch_bounds__(256) void hist_dst(const int* __restrict__ dst, int* cnt, int e) {
  int i = blockIdx.x * 256 + threadIdx.x;
  if (i < e) atomicAdd(&cnt[dst[i]], 1);
}

// zero npad u32 words per row at [r*stride + off .. +npad)
__global__ __launch_bounds__(256) void pad_zero_u32(unsigned* p, int stride, int off, int npad, int rows) {
  int i = blockIdx.x * 256 + threadIdx.x;
  if (i >= rows * npad) return;
  int r = i / npad, j = i - r * npad;
  p[(size_t)r * stride + off + j] = 0u;
}

// ---- 2-level exclusive scan over deg[N] (1024 elems/block) ----
__global__ __launch_bounds__(256) void scanA(const int* __restrict__ deg, int* __restrict__ loc,
                                             int* __restrict__ partials, int n) {
  __shared__ int ts[256];
  int b = blockIdx.x, t = threadIdx.x;
  int base = b * 1024 + t * 4;
  int v[4], s = 0;
#pragma unroll
  for (int j = 0; j < 4; ++j) {
    v[j] = (base + j < n) ? deg[base + j] : 0;
    s += v[j];
  }
  ts[t] = s;
  __syncthreads();
  for (int off = 1; off < 256; off <<= 1) {
    int x = (t >= off) ? ts[t - off] : 0;
    __syncthreads();
    ts[t] += x;
    __syncthreads();
  }
  if (t == 255) partials[b] = ts[255];
  int run = ts[t] - s;  // exclusive
#pragma unroll
  for (int j = 0; j < 4; ++j) {
    if (base + j < n) loc[base + j] = run;
    run += v[j];
  }
}

__global__ __launch_bounds__(512) void scanB(int* partials, int nb) {
  __shared__ int s[512];
  int t = threadIdx.x;
  s[t] = (t < nb) ? partials[t] : 0;
  __syncthreads();
  if (t == 0) {
    int run = 0;
    for (int i = 0; i < nb; ++i) { int v = s[i]; s[i] = run; run += v; }
  }
  __syncthreads();
  if (t < nb) partials[t] = s[t];
}

__global__ __launch_bounds__(256) void scanC(int* __restrict__ rowptr, const int* __restrict__ partials,
                                             int* __restrict__ cur, int n, int e) {
  int i = blockIdx.x * 256 + threadIdx.x;
  if (i < n) {
    int v = rowptr[i] + partials[i >> 10];
    rowptr[i] = v;
    cur[i] = v;
  }
  if (i == 0) rowptr[n] = e;
}

__global__ __launch_bounds__(256) void dinv_k(const int* __restrict__ rowptr, float* dinv, int n) {
  int i = blockIdx.x * 256 + threadIdx.x;
  if (i < n) dinv[i] = rsqrtf(1.0f + (float)(rowptr[i + 1] - rowptr[i]));
}

__global__ __launch_bounds__(256) void bucket(const int* __restrict__ src, const int* __restrict__ dst,
                                              int* __restrict__ cur, int* __restrict__ ssrc, int e) {
  int i = blockIdx.x * 256 + threadIdx.x;
  if (i < e) ssrc[atomicAdd(&cur[dst[i]], 1)] = src[i];
}

// gstart[g] = first node index of graph g (batch sorted); gstart[G] = N
__global__ __launch_bounds__(256) void graph_starts(const int* __restrict__ batch,
                                                    int* __restrict__ gstart, int n) {
  int i = blockIdx.x * 256 + threadIdx.x;
  if (i < n) {
    int b = batch[i];
    int bp = (i == 0) ? -1 : batch[i - 1];
    for (int g = bp + 1; g <= b; ++g) gstart[g] = i;
  } else if (i == n) {
    int bl = batch[n - 1];
    for (int g = bl + 1; g <= N_GRAPHS; ++g) gstart[g] = n;
  }
}

// WT[c][k'] = f16(W[k][c]); CHUNK96: k'=(96-blk) layout, valid (k'%96)<78, k=78*(k'/96)+k'%96
template <int CHUNK96>
__global__ __launch_bounds__(256) void wt_conv(const float* __restrict__ W, _Float16* __restrict__ WT,
                                               int K, int Nout, int ldw, int KP, int total) {
  int i = blockIdx.x * 256 + threadIdx.x;
  if (i >= total) return;
  int c = i / KP, kp = i - c * KP;
  int k; bool valid;
  if (CHUNK96) { int blk = kp / 96, r = kp - blk * 96; k = blk * 78 + r; valid = (r < 78) && (k < K); }
  else { k = kp; valid = kp < K; }
  WT[i] = (valid && c < Nout) ? (_Float16)W[(size_t)k * ldw + c] : (_Float16)0.f;
}

// Xh[n, 0:96] = f16(x[n, 0:78]), zero pad
__global__ __launch_bounds__(256) void xconv(const float* __restrict__ x, _Float16* __restrict__ Xh) {
  unsigned idx = blockIdx.x * 256u + threadIdx.x;
  if (idx >= (unsigned)N_NODES * 48u) return;
  unsigned n = idx / 48u, c2 = idx - n * 48u;
  __half2 h = __floats2half2_rn(0.f, 0.f);
  if (c2 < 39u) {
    float2 v = *reinterpret_cast<const float2*>(x + (size_t)n * 78 + 2 * c2);
    h = __floats2half2_rn(v.x, v.y);
  }
  *reinterpret_cast<__half2*>((__half*)Xh + (size_t)n * 96 + 2 * c2) = h;
}

// Direct-register MFMA GEMM: no LDS, no barriers. in [M,KP] f16 zero-padded;
// WT [*,KP] f16 pre-transposed (L1/L2-cached). Tile 128x80, 4 waves.
// OUT_MODE 0: v*rs[row] -> f16 ; 1: relu(v+bo) -> f16 ; 2: v+bo -> f32
template <int KP, int OUT_MODE>
__global__ __launch_bounds__(256) void gemm_direct(
    const _Float16* __restrict__ in, const _Float16* __restrict__ WT,
    void* __restrict__ outp, const float* __restrict__ rs, const float* __restrict__ bo,
    int M, int Nout, int LDO) {
  constexpr int NS = KP / 32;
  const int tid = threadIdx.x;
  const int lane = tid & 63;
  const int wid = tid >> 6;
  const int row0 = blockIdx.y * 128;
  const int col0 = blockIdx.x * 80;
  const int koff = (lane >> 4) * 8;
  const int gr0 = row0 + wid * 32 + (lane & 15);
  const bool v0 = gr0 < M, v1 = (gr0 + 16) < M;
  const _Float16* a0 = in + (size_t)gr0 * KP + koff;
  const _Float16* a1 = a0 + (size_t)16 * KP;
  const _Float16* bp = WT + (size_t)(col0 + (lane & 15)) * KP + koff;
  const f16x8 zf = {0, 0, 0, 0, 0, 0, 0, 0};
  const f32x4 z4 = {0.f, 0.f, 0.f, 0.f};
  f32x4 acc[2][5];
#pragma unroll
  for (int a = 0; a < 2; ++a)
#pragma unroll
    for (int b = 0; b < 5; ++b) acc[a][b] = z4;

#pragma unroll 3
  for (int s = 0; s < NS; ++s) {
    f16x8 af0 = v0 ? *reinterpret_cast<const f16x8*>(a0 + s * 32) : zf;
    f16x8 af1 = v1 ? *reinterpret_cast<const f16x8*>(a1 + s * 32) : zf;
    f16x8 bf[5];
#pragma unroll
    for (int nf = 0; nf < 5; ++nf)
      bf[nf] = *reinterpret_cast<const f16x8*>(bp + (size_t)nf * 16 * KP + s * 32);
#pragma unroll
    for (int nf = 0; nf < 5; ++nf) {
      acc[0][nf] = __builtin_amdgcn_mfma_f32_16x16x32_f16(af0, bf[nf], acc[0][nf], 0, 0, 0);
      acc[1][nf] = __builtin_amdgcn_mfma_f32_16x16x32_f16(af1, bf[nf], acc[1][nf], 0, 0, 0);
    }
  }

  // epilogue: C/D col=lane&15, row=(lane>>4)*4+reg
#pragma unroll
  for (int rf = 0; rf < 2; ++rf) {
#pragma unroll
    for (int j = 0; j < 4; ++j) {
      int gr = row0 + wid * 32 + rf * 16 + (lane >> 4) * 4 + j;
      if (gr >= M) continue;
      float sc = (OUT_MODE == 0) ? rs[gr] : 0.f;
#pragma unroll
      for (int nf = 0; nf < 5; ++nf) {
        int oc = col0 + nf * 16 + (lane & 15);
        if (oc >= Nout) continue;
        float v = acc[rf][nf][j];
        if (OUT_MODE == 0) {
          ((_Float16*)outp)[(size_t)gr * LDO + oc] = (_Float16)(v * sc);
        } else if (OUT_MODE == 1) {
          ((_Float16*)outp)[(size_t)gr * LDO + oc] = (_Float16)fmaxf(v + bo[oc], 0.f);
        } else {
          ((float*)outp)[(size_t)gr * LDO + oc] = v + bo[oc];
        }
      }
    }
  }
}

__device__ inline void acc8(float* a, uint4 v) {
  const __half2* h = reinterpret_cast<const __half2*>(&v);
#pragma unroll
  for (int j = 0; j < 4; ++j) {
    float2 f = __half22float2(h[j]);
    a[2 * j] += f.x;
    a[2 * j + 1] += f.y;
  }
}

// Fused segment-sum + transform, 16B per thread (10 threads/node, hs stride 80).
// dsth[n, wcoff + q*8 + j] = f16(relu(dinv[n]*(hs[n]+Σ_seg hs[ssrc]) + b[boff+q*8+j]))
// (bias forced 0 for cols >= 78 so pad outputs stay exactly zero)
__global__ __launch_bounds__(256) void aggregate16B(
    const _Float16* __restrict__ hs, const int* __restrict__ rowptr,
    const int* __restrict__ ssrc, const float* __restrict__ dinv,
    const float* __restrict__ b, _Float16* __restrict__ dsth,
    int ldo, int boff, int wcoff) {
  unsigned idx = blockIdx.x * 256u + threadIdx.x;
  if (idx >= (unsigned)N_NODES * 10u) return;
  unsigned n = idx / 10u, q = idx - n * 10u;
  const _Float16* hbase = hs + 8u * q;
  float a[8];
  {
    uint4 sv = *reinterpret_cast<const uint4*>(hbase + (size_t)n * 80);
    const __half2* h = reinterpret_cast<const __half2*>(&sv);
#pragma unroll
    for (int j = 0; j < 4; ++j) {
      float2 f = __half22float2(h[j]);
      a[2 * j] = f.x;
      a[2 * j + 1] = f.y;
    }
  }
  int i = rowptr[n], s1 = rowptr[n + 1];
  for (; i + 2 <= s1; i += 2) {
    uint4 va = *reinterpret_cast<const uint4*>(hbase + (size_t)ssrc[i] * 80);
    uint4 vb = *reinterpret_cast<const uint4*>(hbase + (size_t)ssrc[i + 1] * 80);
    acc8(a, va);
    acc8(a, vb);
  }
  if (i < s1) {
    uint4 va = *reinterpret_cast<const uint4*>(hbase + (size_t)ssrc[i] * 80);
    acc8(a, va);
  }
  float di = dinv[n];
  _Float16 ov[8];
#pragma unroll
  for (int j = 0; j < 8; ++j) {
    int col = q * 8 + j;
    float bv = (col < 78) ? b[boff + col] : 0.f;
    ov[j] = (_Float16)fmaxf(fmaf(di, a[j], bv), 0.f);
  }
  *reinterpret_cast<uint4*>(dsth + (size_t)n * ldo + wcoff + q * 8) =
      *reinterpret_cast<const uint4*>(ov);
}

// Mean-pool over contiguous node range: GA[g, coff96 + 2p..] = (1/cnt) Σ_n TR[n, 2p..]
__global__ __launch_bounds__(256) void pool_seq(
    const _Float16* __restrict__ TR, const int* __restrict__ gstart,
    _Float16* __restrict__ GA, int coff96) {
  unsigned idx = blockIdx.x * 256u + threadIdx.x;
  if (idx >= (unsigned)N_GRAPHS * 39u) return;
  unsigned g = idx / 39u, p = idx - g * 39u;
  int n0 = gstart[g], n1 = gstart[g + 1];
  const __half* base = (const __half*)TR + 2 * p;
  float ax = 0.f, ay = 0.f, bx = 0.f, by = 0.f;
  int n = n0;
  for (; n + 2 <= n1; n += 2) {
    __half2 va = *reinterpret_cast<const __half2*>(base + (size_t)n * 80);
    __half2 vb = *reinterpret_cast<const __half2*>(base + (size_t)(n + 1) * 80);
    ax += __half2float(va.x); ay += __half2float(va.y);
    bx += __half2float(vb.x); by += __half2float(vb.y);
  }
  if (n < n1) {
    __half2 va = *reinterpret_cast<const __half2*>(base + (size_t)n * 80);
    ax += __half2float(va.x); ay += __half2float(va.y);
  }
  float gi = 1.0f / fmaxf((float)(n1 - n0), 1.0f);
  *reinterpret_cast<__half2*>(GA + (size_t)g * 384 + coff96 + 2 * p) =
      __floats2half2_rn((ax + bx) * gi, (ay + by) * gi);
}

extern "C" void kernel_launch(void* const* d_in, const int* in_sizes, int n_in,
                              void* d_out, int out_size, void* d_ws, size_t ws_size,
                              hipStream_t stream) {
  const float* x   = (const float*)d_in[0];
  const int* ei    = (const int*)d_in[1];
  const int* batch = (const int*)d_in[2];
  const float* W1 = (const float*)d_in[3];
  const float* b1 = (const float*)d_in[4];
  const float* W2 = (const float*)d_in[5];
  const float* b2 = (const float*)d_in[6];
  const float* W3 = (const float*)d_in[7];
  const float* b3 = (const float*)d_in[8];
  const float* fW1 = (const float*)d_in[9];
  const float* fb1 = (const float*)d_in[10];
  const float* fW2 = (const float*)d_in[11];
  const float* fb2 = (const float*)d_in[12];
  float* out = (float*)d_out;

  const int Nn = N_NODES, E = N_EDGES, G = N_GRAPHS;
  const int* src = ei;
  const int* dst = ei + E;

  // ---- workspace layout (~396 MB) ----
  // AGG2h [N][2][96] chunk-strided; Xh aliases it; TR aliases AGG1h; fc1 aliases HSh.
  _Float16* AGG2h = (_Float16*)d_ws;                      // [N,192]
  _Float16* Xh    = AGG2h;                                // [N,96]  (dead after L1 gemm)
  _Float16* AGG1h = AGG2h + (size_t)Nn * 192;             // [N,96]
  _Float16* TR    = AGG1h;                                // [N,80]  (after L2 gemms done)
  _Float16* HSh   = AGG1h + (size_t)Nn * 96;              // [N,80]
  _Float16* fc1   = HSh;                                  // [G,1056] (after last L3 agg)
  _Float16* GA    = HSh + (size_t)Nn * 80;                // [G,384] chunk-strided
  _Float16* W1T   = GA + (size_t)G * 384;                 // [80][96]
  _Float16* W2T   = W1T + 80 * 96;                        // [160][96]
  _Float16* W3T   = W2T + 160 * 96;                       // [320][192] chunk96
  _Float16* fW1T  = W3T + 320 * 192;                      // [1040][384] chunk96
  _Float16* fW2T  = fW1T + (size_t)1040 * 384;            // [160][1056]
  float* dinv     = (float*)(fW2T + (size_t)160 * 1056);  // [N]
  int* rowptr     = (int*)(dinv + Nn);                    // [N+1]
  int* cur        = rowptr + Nn + 1;                      // [N]
  int* ssrc       = cur + Nn;                             // [E]
  int* partials   = ssrc + E;                             // [512]
  int* gstart     = partials + 512;                       // [G+1]

  dim3 blk(256);
  const int gN10 = (int)(((unsigned)Nn * 10u + 255u) / 256u);
  const int gG39 = (int)(((unsigned)G * 39u + 255u) / 256u);
  const dim3 nodeGrid(1, (Nn + 127) / 128);
  const int NB = (Nn + 1023) / 1024;  // 489

  // ---- CSR build (dst-sorted src list) ----
  fill_u32<<<(Nn + 255) / 256, blk, 0, stream>>>((unsigned*)cur, 0u, Nn);
  hist_dst<<<(E + 255) / 256, blk, 0, stream>>>(dst, cur, E);
  scanA<<<NB, blk, 0, stream>>>(cur, rowptr, partials, Nn);
  scanB<<<1, 512, 0, stream>>>(partials, NB);
  scanC<<<(Nn + 255) / 256, blk, 0, stream>>>(rowptr, partials, cur, Nn, E);
  dinv_k<<<(Nn + 255) / 256, blk, 0, stream>>>(rowptr, dinv, Nn);
  bucket<<<(E + 255) / 256, blk, 0, stream>>>(src, dst, cur, ssrc, E);
  graph_starts<<<(Nn + 256) / 256, blk, 0, stream>>>(batch, gstart, Nn);

  // ---- fp16 transposed weights ----
  wt_conv<0><<<(80 * 96 + 255) / 256, blk, 0, stream>>>(W1, W1T, 78, 78, 78, 96, 80 * 96);
  wt_conv<0><<<(160 * 96 + 255) / 256, blk, 0, stream>>>(W2, W2T, 78, 156, 156, 96, 160 * 96);
  wt_conv<1><<<(320 * 192 + 255) / 256, blk, 0, stream>>>(W3, W3T, 156, 312, 312, 192, 320 * 192);
  wt_conv<1><<<(1040 * 384 + 255) / 256, blk, 0, stream>>>(fW1, fW1T, 312, 1024, 1024, 384, 1040 * 384);
  wt_conv<0><<<(160 * 1056 + 255) / 256, blk, 0, stream>>>(fW2, fW2T, 1024, 128, 128, 1056, 160 * 1056);

  // ---- pads: HSh cols 78..79; AGG1h 80..95; AGG2h chunk pads 80..95/176..191;
  //      GA chunk pads (4x). (ws poisoned 0xAA once) ----
  pad_zero_u32<<<(Nn + 255) / 256, blk, 0, stream>>>((unsigned*)HSh, 40, 39, 1, Nn);
  pad_zero_u32<<<((Nn * 8) + 255) / 256, blk, 0, stream>>>((unsigned*)AGG1h, 48, 40, 8, Nn);
  pad_zero_u32<<<((Nn * 8) + 255) / 256, blk, 0, stream>>>((unsigned*)AGG2h, 96, 40, 8, Nn);
  pad_zero_u32<<<((Nn * 8) + 255) / 256, blk, 0, stream>>>((unsigned*)AGG2h, 96, 88, 8, Nn);
  for (int c = 0; c < 4; ++c)
    pad_zero_u32<<<((G * 9) + 255) / 256, blk, 0, stream>>>((unsigned*)GA, 192, 48 * c + 39, 9, G);

  // ---- x -> f16 [N,96] ----
  xconv<<<(int)(((unsigned)Nn * 48u + 255u) / 256u), blk, 0, stream>>>(x, Xh);

  // ---- layer 1 ----
  gemm_direct<96, 0><<<nodeGrid, blk, 0, stream>>>(Xh, W1T, HSh, dinv, nullptr, Nn, 78, 80);
  aggregate16B<<<gN10, blk, 0, stream>>>(HSh, rowptr, ssrc, dinv, b1, AGG1h, 96, 0, 0);

  // ---- layer 2 (2 chunks of 78 -> AGG2h chunk-strided) ----
  for (int c = 0; c < 2; ++c) {
    gemm_direct<96, 0><<<nodeGrid, blk, 0, stream>>>(
        AGG1h, W2T + (size_t)(78 * c) * 96, HSh, dinv, nullptr, Nn, 78, 80);
    aggregate16B<<<gN10, blk, 0, stream>>>(HSh, rowptr, ssrc, dinv, b2, AGG2h, 192, 78 * c, 96 * c);
  }

  // ---- layer 3 (4 chunks): gemm -> relu-transform (TR) -> seq pool ----
  for (int c = 0; c < 4; ++c) {
    gemm_direct<192, 0><<<nodeGrid, blk, 0, stream>>>(
        AGG2h, W3T + (size_t)(78 * c) * 192, HSh, dinv, nullptr, Nn, 78, 80);
    aggregate16B<<<gN10, blk, 0, stream>>>(HSh, rowptr, ssrc, dinv, b3, TR, 80, 78 * c, 0);
    pool_seq<<<gG39, blk, 0, stream>>>(TR, gstart, GA, 96 * c);
  }

  // ---- fc1 pad cols (1024..1055); HSh dead after last aggregate ----
  pad_zero_u32<<<((G * 16) + 255) / 256, blk, 0, stream>>>((unsigned*)fc1, 528, 512, 16, G);

  // ---- FC1: relu(GA @ fW1 + fb1) -> fc1 f16 ----
  {
    dim3 g((1024 + 79) / 80, (G + 127) / 128);  // 13 x 157
    gemm_direct<384, 1><<<g, blk, 0, stream>>>(GA, fW1T, fc1, nullptr, fb1, G, 1024, 1056);
  }
  // ---- FC2: out = fc1 @ fW2 + fb2 (f32) ----
  {
    dim3 g((128 + 79) / 80, (G + 127) / 128);  // 2 x 157
    gemm_direct<1056, 2><<<g, blk, 0, stream>>>(fc1, fW2T, out, nullptr, fb2, G, 128, 128);
  }
}

// Round 9
// 1535.371 us; speedup vs baseline: 1.5136x; 1.0879x over previous
//
#include <hip/hip_runtime.h>
#include <hip/hip_fp16.h>

#define N_NODES 500000
#define N_EDGES 1000000
#define N_GRAPHS 20000

typedef _Float16 f16x8 __attribute__((ext_vector_type(8)));
typedef float f32x4 __attribute__((ext_vector_type(4)));

__global__ __launch_bounds__(256) void fill_u32(unsigned* p, unsigned v, int n) {
  int i = blockIdx.x * 256 + threadIdx.x;
  if (i < n) p[i] = v;
}

__global__ __launch_bounds__(256) void hist_dst(const int* __restrict__ dst, int* cnt, int e) {
  int i = blockIdx.x * 256 + threadIdx.x;
  if (i < e) atomicAdd(&cnt[dst[i]], 1);
}

// zero npad u32 words per row at [r*stride + off .. +npad)
__global__ __launch_bounds__(256) void pad_zero_u32(unsigned* p, int stride, int off, int npad, int rows) {
  int i = blockIdx.x * 256 + threadIdx.x;
  if (i >= rows * npad) return;
  int r = i / npad, j = i - r * npad;
  p[(size_t)r * stride + off + j] = 0u;
}

// ---- 2-level exclusive scan over deg[N] (1024 elems/block) ----
__global__ __launch_bounds__(256) void scanA(const int* __restrict__ deg, int* __restrict__ loc,
                                             int* __restrict__ partials, int n) {
  __shared__ int ts[256];
  int b = blockIdx.x, t = threadIdx.x;
  int base = b * 1024 + t * 4;
  int v[4], s = 0;
#pragma unroll
  for (int j = 0; j < 4; ++j) {
    v[j] = (base + j < n) ? deg[base + j] : 0;
    s += v[j];
  }
  ts[t] = s;
  __syncthreads();
  for (int off = 1; off < 256; off <<= 1) {
    int x = (t >= off) ? ts[t - off] : 0;
    __syncthreads();
    ts[t] += x;
    __syncthreads();
  }
  if (t == 255) partials[b] = ts[255];
  int run = ts[t] - s;  // exclusive
#pragma unroll
  for (int j = 0; j < 4; ++j) {
    if (base + j < n) loc[base + j] = run;
    run += v[j];
  }
}

__global__ __launch_bounds__(512) void scanB(int* partials, int nb) {
  __shared__ int s[512];
  int t = threadIdx.x;
  s[t] = (t < nb) ? partials[t] : 0;
  __syncthreads();
  if (t == 0) {
    int run = 0;
    for (int i = 0; i < nb; ++i) { int v = s[i]; s[i] = run; run += v; }
  }
  __syncthreads();
  if (t < nb) partials[t] = s[t];
}

__global__ __launch_bounds__(256) void scanC(int* __restrict__ rowptr, const int* __restrict__ partials,
                                             int* __restrict__ cur, int n, int e) {
  int i = blockIdx.x * 256 + threadIdx.x;
  if (i < n) {
    int v = rowptr[i] + partials[i >> 10];
    rowptr[i] = v;
    cur[i] = v;
  }
  if (i == 0) rowptr[n] = e;
}

__global__ __launch_bounds__(256) void dinv_k(const int* __restrict__ rowptr, float* dinv, int n) {
  int i = blockIdx.x * 256 + threadIdx.x;
  if (i < n) dinv[i] = rsqrtf(1.0f + (float)(rowptr[i + 1] - rowptr[i]));
}

__global__ __launch_bounds__(256) void bucket(const int* __restrict__ src, const int* __restrict__ dst,
                                              int* __restrict__ cur, int* __restrict__ ssrc, int e) {
  int i = blockIdx.x * 256 + threadIdx.x;
  if (i < e) ssrc[atomicAdd(&cur[dst[i]], 1)] = src[i];
}

// gstart[g] = first node index of graph g (batch sorted); gstart[G] = N
__global__ __launch_bounds__(256) void graph_starts(const int* __restrict__ batch,
                                                    int* __restrict__ gstart, int n) {
  int i = blockIdx.x * 256 + threadIdx.x;
  if (i < n) {
    int b = batch[i];
    int bp = (i == 0) ? -1 : batch[i - 1];
    for (int g = bp + 1; g <= b; ++g) gstart[g] = i;
  } else if (i == n) {
    int bl = batch[n - 1];
    for (int g = bl + 1; g <= N_GRAPHS; ++g) gstart[g] = n;
  }
}

// WT[c][k'] = f16(W[k][c]); CHUNK96: k'=(96-blk) layout, valid (k'%96)<78, k=78*(k'/96)+k'%96
template <int CHUNK96>
__global__ __launch_bounds__(256) void wt_conv(const float* __restrict__ W, _Float16* __restrict__ WT,
                                               int K, int Nout, int ldw, int KP, int total) {
  int i = blockIdx.x * 256 + threadIdx.x;
  if (i >= total) return;
  int c = i / KP, kp = i - c * KP;
  int k; bool valid;
  if (CHUNK96) { int blk = kp / 96, r = kp - blk * 96; k = blk * 78 + r; valid = (r < 78) && (k < K); }
  else { k = kp; valid = kp < K; }
  WT[i] = (valid && c < Nout) ? (_Float16)W[(size_t)k * ldw + c] : (_Float16)0.f;
}

// Xh[n, 0:96] = f16(x[n, 0:78]), zero pad
__global__ __launch_bounds__(256) void xconv(const float* __restrict__ x, _Float16* __restrict__ Xh) {
  unsigned idx = blockIdx.x * 256u + threadIdx.x;
  if (idx >= (unsigned)N_NODES * 48u) return;
  unsigned n = idx / 48u, c2 = idx - n * 48u;
  __half2 h = __floats2half2_rn(0.f, 0.f);
  if (c2 < 39u) {
    float2 v = *reinterpret_cast<const float2*>(x + (size_t)n * 78 + 2 * c2);
    h = __floats2half2_rn(v.x, v.y);
  }
  *reinterpret_cast<__half2*>((__half*)Xh + (size_t)n * 96 + 2 * c2) = h;
}

// Direct-register MFMA GEMM. in [M,KP] f16 zero-padded; WT [*,KP] f16 pre-transposed
// (rows padded to multiple of 80, zeros). Tile 128x80, 4 waves.
// BLDS=1: stage B once in LDS in fragment-linear order (lane i at byte 16*i ->
// sequential ds_read_b128, conflict-free), single barrier, no in-loop barriers.
// OUT_MODE 0: v*rs[row] -> f16 ; 1: relu(v+bo) -> f16 ; 2: v+bo -> f32
template <int KP, int OUT_MODE, int BLDS>
__global__ __launch_bounds__(256) void gemm_direct(
    const _Float16* __restrict__ in, const _Float16* __restrict__ WT,
    void* __restrict__ outp, const float* __restrict__ rs, const float* __restrict__ bo,
    int M, int Nout, int LDO) {
  constexpr int NS = KP / 32;
  __shared__ _Float16 Bs[BLDS ? 5 * NS * 64 * 8 : 8];
  const int tid = threadIdx.x;
  const int lane = tid & 63;
  const int wid = tid >> 6;
  const int row0 = blockIdx.y * 128;
  const int col0 = blockIdx.x * 80;
  const int koff = (lane >> 4) * 8;
  const int gr0 = row0 + wid * 32 + (lane & 15);
  const bool v0 = gr0 < M, v1 = (gr0 + 16) < M;
  const _Float16* a0 = in + (size_t)gr0 * KP + koff;
  const _Float16* a1 = a0 + (size_t)16 * KP;
  const _Float16* bp = WT + (size_t)(col0 + (lane & 15)) * KP + koff;

  if (BLDS) {
    // stage all 5*NS*64 B-fragments: frag i -> lane i&63, nf (i>>6)%5, step i/320
    for (int i = tid; i < 5 * NS * 64; i += 256) {
      int l = i & 63;
      int nf = (i >> 6) % 5;
      int s = i / 320;
      int col = col0 + nf * 16 + (l & 15);
      int k = s * 32 + ((l >> 4) << 3);
      *reinterpret_cast<uint4*>(&Bs[(size_t)i * 8]) =
          *reinterpret_cast<const uint4*>(WT + (size_t)col * KP + k);
    }
    __syncthreads();
  }

  const f16x8 zf = {0, 0, 0, 0, 0, 0, 0, 0};
  const f32x4 z4 = {0.f, 0.f, 0.f, 0.f};
  f32x4 acc[2][5];
#pragma unroll
  for (int a = 0; a < 2; ++a)
#pragma unroll
    for (int b = 0; b < 5; ++b) acc[a][b] = z4;

#pragma unroll
  for (int s = 0; s < NS; ++s) {
    f16x8 af0 = v0 ? *reinterpret_cast<const f16x8*>(a0 + s * 32) : zf;
    f16x8 af1 = v1 ? *reinterpret_cast<const f16x8*>(a1 + s * 32) : zf;
    f16x8 bf[5];
#pragma unroll
    for (int nf = 0; nf < 5; ++nf) {
      if (BLDS)
        bf[nf] = *reinterpret_cast<const f16x8*>(&Bs[((size_t)(s * 5 + nf) * 64 + lane) * 8]);
      else
        bf[nf] = *reinterpret_cast<const f16x8*>(bp + (size_t)nf * 16 * KP + s * 32);
    }
#pragma unroll
    for (int nf = 0; nf < 5; ++nf) {
      acc[0][nf] = __builtin_amdgcn_mfma_f32_16x16x32_f16(af0, bf[nf], acc[0][nf], 0, 0, 0);
      acc[1][nf] = __builtin_amdgcn_mfma_f32_16x16x32_f16(af1, bf[nf], acc[1][nf], 0, 0, 0);
    }
  }

  // epilogue: C/D col=lane&15, row=(lane>>4)*4+reg
#pragma unroll
  for (int rf = 0; rf < 2; ++rf) {
#pragma unroll
    for (int j = 0; j < 4; ++j) {
      int gr = row0 + wid * 32 + rf * 16 + (lane >> 4) * 4 + j;
      if (gr >= M) continue;
      float sc = (OUT_MODE == 0) ? rs[gr] : 0.f;
#pragma unroll
      for (int nf = 0; nf < 5; ++nf) {
        int oc = col0 + nf * 16 + (lane & 15);
        if (oc >= Nout) continue;
        float v = acc[rf][nf][j];
        if (OUT_MODE == 0) {
          ((_Float16*)outp)[(size_t)gr * LDO + oc] = (_Float16)(v * sc);
        } else if (OUT_MODE == 1) {
          ((_Float16*)outp)[(size_t)gr * LDO + oc] = (_Float16)fmaxf(v + bo[oc], 0.f);
        } else {
          ((float*)outp)[(size_t)gr * LDO + oc] = v + bo[oc];
        }
      }
    }
  }
}

__device__ inline void acc8(float* a, uint4 v) {
  const __half2* h = reinterpret_cast<const __half2*>(&v);
#pragma unroll
  for (int j = 0; j < 4; ++j) {
    float2 f = __half22float2(h[j]);
    a[2 * j] += f.x;
    a[2 * j + 1] += f.y;
  }
}

// Fused segment-sum + transform, 16B per thread (10 threads/node, hs stride 80).
// dsth[n, wcoff + q*8 + j] = f16(relu(dinv[n]*(hs[n]+Σ_seg hs[ssrc]) + b[boff+q*8+j]))
// (bias forced 0 for cols >= 78 so pad outputs stay exactly zero)
__global__ __launch_bounds__(256) void aggregate16B(
    const _Float16* __restrict__ hs, const int* __restrict__ rowptr,
    const int* __restrict__ ssrc, const float* __restrict__ dinv,
    const float* __restrict__ b, _Float16* __restrict__ dsth,
    int ldo, int boff, int wcoff) {
  unsigned idx = blockIdx.x * 256u + threadIdx.x;
  if (idx >= (unsigned)N_NODES * 10u) return;
  unsigned n = idx / 10u, q = idx - n * 10u;
  const _Float16* hbase = hs + 8u * q;
  float a[8];
  {
    uint4 sv = *reinterpret_cast<const uint4*>(hbase + (size_t)n * 80);
    const __half2* h = reinterpret_cast<const __half2*>(&sv);
#pragma unroll
    for (int j = 0; j < 4; ++j) {
      float2 f = __half22float2(h[j]);
      a[2 * j] = f.x;
      a[2 * j + 1] = f.y;
    }
  }
  int i = rowptr[n], s1 = rowptr[n + 1];
  for (; i + 2 <= s1; i += 2) {
    uint4 va = *reinterpret_cast<const uint4*>(hbase + (size_t)ssrc[i] * 80);
    uint4 vb = *reinterpret_cast<const uint4*>(hbase + (size_t)ssrc[i + 1] * 80);
    acc8(a, va);
    acc8(a, vb);
  }
  if (i < s1) {
    uint4 va = *reinterpret_cast<const uint4*>(hbase + (size_t)ssrc[i] * 80);
    acc8(a, va);
  }
  float di = dinv[n];
  _Float16 ov[8];
#pragma unroll
  for (int j = 0; j < 8; ++j) {
    int col = q * 8 + j;
    float bv = (col < 78) ? b[boff + col] : 0.f;
    ov[j] = (_Float16)fmaxf(fmaf(di, a[j], bv), 0.f);
  }
  *reinterpret_cast<uint4*>(dsth + (size_t)n * ldo + wcoff + q * 8) =
      *reinterpret_cast<const uint4*>(ov);
}

// Mean-pool over contiguous node range: GA[g, coff96 + 2p..] = (1/cnt) Σ_n TR[n, 2p..]
__global__ __launch_bounds__(256) void pool_seq(
    const _Float16* __restrict__ TR, const int* __restrict__ gstart,
    _Float16* __restrict__ GA, int coff96) {
  unsigned idx = blockIdx.x * 256u + threadIdx.x;
  if (idx >= (unsigned)N_GRAPHS * 39u) return;
  unsigned g = idx / 39u, p = idx - g * 39u;
  int n0 = gstart[g], n1 = gstart[g + 1];
  const __half* base = (const __half*)TR + 2 * p;
  float ax = 0.f, ay = 0.f, bx = 0.f, by = 0.f;
  int n = n0;
  for (; n + 2 <= n1; n += 2) {
    __half2 va = *reinterpret_cast<const __half2*>(base + (size_t)n * 80);
    __half2 vb = *reinterpret_cast<const __half2*>(base + (size_t)(n + 1) * 80);
    ax += __half2float(va.x); ay += __half2float(va.y);
    bx += __half2float(vb.x); by += __half2float(vb.y);
  }
  if (n < n1) {
    __half2 va = *reinterpret_cast<const __half2*>(base + (size_t)n * 80);
    ax += __half2float(va.x); ay += __half2float(va.y);
  }
  float gi = 1.0f / fmaxf((float)(n1 - n0), 1.0f);
  *reinterpret_cast<__half2*>(GA + (size_t)g * 384 + coff96 + 2 * p) =
      __floats2half2_rn((ax + bx) * gi, (ay + by) * gi);
}

extern "C" void kernel_launch(void* const* d_in, const int* in_sizes, int n_in,
                              void* d_out, int out_size, void* d_ws, size_t ws_size,
                              hipStream_t stream) {
  const float* x   = (const float*)d_in[0];
  const int* ei    = (const int*)d_in[1];
  const int* batch = (const int*)d_in[2];
  const float* W1 = (const float*)d_in[3];
  const float* b1 = (const float*)d_in[4];
  const float* W2 = (const float*)d_in[5];
  const float* b2 = (const float*)d_in[6];
  const float* W3 = (const float*)d_in[7];
  const float* b3 = (const float*)d_in[8];
  const float* fW1 = (const float*)d_in[9];
  const float* fb1 = (const float*)d_in[10];
  const float* fW2 = (const float*)d_in[11];
  const float* fb2 = (const float*)d_in[12];
  float* out = (float*)d_out;

  const int Nn = N_NODES, E = N_EDGES, G = N_GRAPHS;
  const int* src = ei;
  const int* dst = ei + E;

  // ---- workspace layout (~396 MB) ----
  // AGG2h [N][2][96] chunk-strided; Xh aliases it; TR aliases AGG1h; fc1 aliases HSh.
  _Float16* AGG2h = (_Float16*)d_ws;                      // [N,192]
  _Float16* Xh    = AGG2h;                                // [N,96]  (dead after L1 gemm)
  _Float16* AGG1h = AGG2h + (size_t)Nn * 192;             // [N,96]
  _Float16* TR    = AGG1h;                                // [N,80]  (after L2 gemms done)
  _Float16* HSh   = AGG1h + (size_t)Nn * 96;              // [N,80]
  _Float16* fc1   = HSh;                                  // [G,1056] (after last L3 agg)
  _Float16* GA    = HSh + (size_t)Nn * 80;                // [G,384] chunk-strided
  _Float16* W1T   = GA + (size_t)G * 384;                 // [80][96]
  _Float16* W2T   = W1T + 80 * 96;                        // [160][96]
  _Float16* W3T   = W2T + 160 * 96;                       // [320][192] chunk96
  _Float16* fW1T  = W3T + 320 * 192;                      // [1040][384] chunk96
  _Float16* fW2T  = fW1T + (size_t)1040 * 384;            // [160][1056]
  float* dinv     = (float*)(fW2T + (size_t)160 * 1056);  // [N]
  int* rowptr     = (int*)(dinv + Nn);                    // [N+1]
  int* cur        = rowptr + Nn + 1;                      // [N]
  int* ssrc       = cur + Nn;                             // [E]
  int* partials   = ssrc + E;                             // [512]
  int* gstart     = partials + 512;                       // [G+1]

  dim3 blk(256);
  const int gN10 = (int)(((unsigned)Nn * 10u + 255u) / 256u);
  const int gG39 = (int)(((unsigned)G * 39u + 255u) / 256u);
  const dim3 nodeGrid(1, (Nn + 127) / 128);
  const int NB = (Nn + 1023) / 1024;  // 489

  // ---- CSR build (dst-sorted src list) ----
  fill_u32<<<(Nn + 255) / 256, blk, 0, stream>>>((unsigned*)cur, 0u, Nn);
  hist_dst<<<(E + 255) / 256, blk, 0, stream>>>(dst, cur, E);
  scanA<<<NB, blk, 0, stream>>>(cur, rowptr, partials, Nn);
  scanB<<<1, 512, 0, stream>>>(partials, NB);
  scanC<<<(Nn + 255) / 256, blk, 0, stream>>>(rowptr, partials, cur, Nn, E);
  dinv_k<<<(Nn + 255) / 256, blk, 0, stream>>>(rowptr, dinv, Nn);
  bucket<<<(E + 255) / 256, blk, 0, stream>>>(src, dst, cur, ssrc, E);
  graph_starts<<<(Nn + 256) / 256, blk, 0, stream>>>(batch, gstart, Nn);

  // ---- fp16 transposed weights ----
  wt_conv<0><<<(80 * 96 + 255) / 256, blk, 0, stream>>>(W1, W1T, 78, 78, 78, 96, 80 * 96);
  wt_conv<0><<<(160 * 96 + 255) / 256, blk, 0, stream>>>(W2, W2T, 78, 156, 156, 96, 160 * 96);
  wt_conv<1><<<(320 * 192 + 255) / 256, blk, 0, stream>>>(W3, W3T, 156, 312, 312, 192, 320 * 192);
  wt_conv<1><<<(1040 * 384 + 255) / 256, blk, 0, stream>>>(fW1, fW1T, 312, 1024, 1024, 384, 1040 * 384);
  wt_conv<0><<<(160 * 1056 + 255) / 256, blk, 0, stream>>>(fW2, fW2T, 1024, 128, 128, 1056, 160 * 1056);

  // ---- pads: HSh cols 78..79; AGG1h 80..95; AGG2h chunk pads 80..95/176..191;
  //      GA chunk pads (4x). (ws poisoned 0xAA once) ----
  pad_zero_u32<<<(Nn + 255) / 256, blk, 0, stream>>>((unsigned*)HSh, 40, 39, 1, Nn);
  pad_zero_u32<<<((Nn * 8) + 255) / 256, blk, 0, stream>>>((unsigned*)AGG1h, 48, 40, 8, Nn);
  pad_zero_u32<<<((Nn * 8) + 255) / 256, blk, 0, stream>>>((unsigned*)AGG2h, 96, 40, 8, Nn);
  pad_zero_u32<<<((Nn * 8) + 255) / 256, blk, 0, stream>>>((unsigned*)AGG2h, 96, 88, 8, Nn);
  for (int c = 0; c < 4; ++c)
    pad_zero_u32<<<((G * 9) + 255) / 256, blk, 0, stream>>>((unsigned*)GA, 192, 48 * c + 39, 9, G);

  // ---- x -> f16 [N,96] ----
  xconv<<<(int)(((unsigned)Nn * 48u + 255u) / 256u), blk, 0, stream>>>(x, Xh);

  // ---- layer 1 ----
  gemm_direct<96, 0, 1><<<nodeGrid, blk, 0, stream>>>(Xh, W1T, HSh, dinv, nullptr, Nn, 78, 80);
  aggregate16B<<<gN10, blk, 0, stream>>>(HSh, rowptr, ssrc, dinv, b1, AGG1h, 96, 0, 0);

  // ---- layer 2 (2 chunks of 78 -> AGG2h chunk-strided) ----
  for (int c = 0; c < 2; ++c) {
    gemm_direct<96, 0, 1><<<nodeGrid, blk, 0, stream>>>(
        AGG1h, W2T + (size_t)(78 * c) * 96, HSh, dinv, nullptr, Nn, 78, 80);
    aggregate16B<<<gN10, blk, 0, stream>>>(HSh, rowptr, ssrc, dinv, b2, AGG2h, 192, 78 * c, 96 * c);
  }

  // ---- layer 3 (4 chunks): gemm -> relu-transform (TR) -> seq pool ----
  for (int c = 0; c < 4; ++c) {
    gemm_direct<192, 0, 1><<<nodeGrid, blk, 0, stream>>>(
        AGG2h, W3T + (size_t)(78 * c) * 192, HSh, dinv, nullptr, Nn, 78, 80);
    aggregate16B<<<gN10, blk, 0, stream>>>(HSh, rowptr, ssrc, dinv, b3, TR, 80, 78 * c, 0);
    pool_seq<<<gG39, blk, 0, stream>>>(TR, gstart, GA, 96 * c);
  }

  // ---- fc1 pad cols (1024..1055); HSh dead after last aggregate ----
  pad_zero_u32<<<((G * 16) + 255) / 256, blk, 0, stream>>>((unsigned*)fc1, 528, 512, 16, G);

  // ---- FC1: relu(GA @ fW1 + fb1) -> fc1 f16 ----
  {
    dim3 g((1024 + 79) / 80, (G + 127) / 128);  // 13 x 157
    gemm_direct<384, 1, 0><<<g, blk, 0, stream>>>(GA, fW1T, fc1, nullptr, fb1, G, 1024, 1056);
  }
  // ---- FC2: out = fc1 @ fW2 + fb2 (f32) ----
  {
    dim3 g((128 + 79) / 80, (G + 127) / 128);  // 2 x 157
    gemm_direct<1056, 2, 0><<<g, blk, 0, stream>>>(fc1, fW2T, out, nullptr, fb2, G, 128, 128);
  }
}